// Round 1
// baseline (189.657 us; speedup 1.0000x reference)
//
#include <hip/hip_runtime.h>

// BiPointNet: 3x (binarized 1x1 conv + BN(batch stats) + ReLU) + maxpool over K.
// B=8, N=1024, K=32, Cin=64, layer sizes 64->64->64->128.
// All activations/weights binarize to {-1,0,+1} with Cin=64 -> 64-bit masks +
// popcount GEMM. BN stats via exact integer sums (deterministic atomics).

#define P_TOTAL (8192 * 32)   // positions q = m*32 + k, m in [0,8192)
#define NROWS 8192
#define KNEI 32

// ---------------- K0: pack weights into bitmasks, zero stats ----------------
__global__ void k0_pack(const float* __restrict__ W1, const float* __restrict__ W2,
                        const float* __restrict__ W3,
                        ulonglong2* __restrict__ wp1, ulonglong2* __restrict__ wp2,
                        ulonglong2* __restrict__ wp3, int* __restrict__ stats) {
    int t = threadIdx.x;
    stats[t] = 0;
    stats[t + 256] = 0;
    if (t < 64) {
        // layer 1: sign/nonzero form
        unsigned long long s = 0, nz = 0;
        for (int i = 0; i < 64; ++i) {
            float w = W1[t * 64 + i];
            if (w > 0.f) s |= 1ull << i;
            if (w != 0.f) nz |= 1ull << i;
        }
        wp1[t] = make_ulonglong2(s, nz);
    } else if (t < 128) {
        // layer 2: pos/neg form (activations are {0,1})
        int o = t - 64;
        unsigned long long pos = 0, neg = 0;
        for (int i = 0; i < 64; ++i) {
            float w = W2[o * 64 + i];
            if (w > 0.f) pos |= 1ull << i;
            if (w < 0.f) neg |= 1ull << i;
        }
        wp2[o] = make_ulonglong2(pos, neg);
    } else {
        // layer 3: pos/neg form, 128 rows
        int o = t - 128;
        unsigned long long pos = 0, neg = 0;
        for (int i = 0; i < 64; ++i) {
            float w = W3[o * 64 + i];
            if (w > 0.f) pos |= 1ull << i;
            if (w < 0.f) neg |= 1ull << i;
        }
        wp3[o] = make_ulonglong2(pos, neg);
    }
}

// ------------- K1: pack input activations (ballot) + layer-1 stats ----------
__global__ void __launch_bounds__(256) k1_pack_stats(
    const float* __restrict__ in, const ulonglong2* __restrict__ wp1,
    ulonglong2* __restrict__ A1, int* __restrict__ sd_g, int* __restrict__ sq_g) {
    const int lane = threadIdx.x & 63;
    const int wib = threadIdx.x >> 6;
    const int nwaves = (gridDim.x * blockDim.x) >> 6;
    int wid = (blockIdx.x * blockDim.x + threadIdx.x) >> 6;

    const ulonglong2 w = wp1[lane];   // .x = sign, .y = nonzero
    int sd = 0, sq = 0;
    for (int q = wid; q < P_TOTAL; q += nwaves) {
        float v = in[(size_t)q * 64 + lane];
        unsigned long long as = __ballot(v > 0.f);
        unsigned long long an = __ballot(v != 0.f);
        if (lane == 0) A1[q] = make_ulonglong2(as, an);
        unsigned long long mnz = an & w.y;
        int dot = __popcll(mnz) - 2 * __popcll(mnz & (as ^ w.x));
        sd += dot;
        sq += dot * dot;
    }
    __shared__ int rd[4][64], rq[4][64];
    rd[wib][lane] = sd;
    rq[wib][lane] = sq;
    __syncthreads();
    if (threadIdx.x < 64) {
        int td = rd[0][lane] + rd[1][lane] + rd[2][lane] + rd[3][lane];
        int tq = rq[0][lane] + rq[1][lane] + rq[2][lane] + rq[3][lane];
        atomicAdd(&sd_g[lane], td);
        atomicAdd(&sq_g[lane], tq);
    }
}

// ----- Kf: fold BN(batch stats)+scale+gamma+beta into v = alpha*dot + bias --
__global__ void kf_finalize(const int* __restrict__ sd, const int* __restrict__ sq,
                            const float* __restrict__ scale, const float* __restrict__ gamma,
                            const float* __restrict__ beta,
                            float* __restrict__ alpha, float* __restrict__ bias, int C) {
    int o = threadIdx.x;
    if (o < C) {
        const double invN = 1.0 / (double)P_TOTAL;
        double m = (double)sd[o] * invN;
        double var = (double)sq[o] * invN - m * m;
        double sc = (double)scale[o];
        double vy = sc * sc * var;
        double inv = 1.0 / sqrt(vy + 1e-5);
        double g = (double)gamma[o];
        alpha[o] = (float)(g * inv * sc);
        bias[o] = (float)((double)beta[o] - g * inv * (sc * m));
    }
}

// -------- K2: layer-1 binarize -> A2 masks, layer-2 dot stats ---------------
__global__ void __launch_bounds__(256) k2_bin1_stats2(
    const ulonglong2* __restrict__ A1, const ulonglong2* __restrict__ wp1,
    const ulonglong2* __restrict__ wp2, const float* __restrict__ alpha1,
    const float* __restrict__ bias1, unsigned long long* __restrict__ A2,
    int* __restrict__ sd_g, int* __restrict__ sq_g) {
    const int lane = threadIdx.x & 63;
    const int wib = threadIdx.x >> 6;
    const int nwaves = (gridDim.x * blockDim.x) >> 6;
    int wid = (blockIdx.x * blockDim.x + threadIdx.x) >> 6;

    const ulonglong2 w1 = wp1[lane];
    const ulonglong2 w2 = wp2[lane];   // .x = pos, .y = neg
    const float a1 = alpha1[lane], b1 = bias1[lane];
    int sd = 0, sq = 0;
    for (int q = wid; q < P_TOTAL; q += nwaves) {
        ulonglong2 a = A1[q];
        unsigned long long mnz = a.y & w1.y;
        int dot1 = __popcll(mnz) - 2 * __popcll(mnz & (a.x ^ w1.x));
        float v = a1 * (float)dot1 + b1;
        unsigned long long A = __ballot(v > 0.f);
        if (lane == 0) A2[q] = A;
        int dot2 = __popcll(A & w2.x) - __popcll(A & w2.y);
        sd += dot2;
        sq += dot2 * dot2;
    }
    __shared__ int rd[4][64], rq[4][64];
    rd[wib][lane] = sd;
    rq[wib][lane] = sq;
    __syncthreads();
    if (threadIdx.x < 64) {
        int td = rd[0][lane] + rd[1][lane] + rd[2][lane] + rd[3][lane];
        int tq = rq[0][lane] + rq[1][lane] + rq[2][lane] + rq[3][lane];
        atomicAdd(&sd_g[lane], td);
        atomicAdd(&sq_g[lane], tq);
    }
}

// -------- K3: layer-2 binarize -> A3 masks, layer-3 dot stats (128 ch) ------
__global__ void __launch_bounds__(256) k3_bin2_stats3(
    const unsigned long long* __restrict__ A2, const ulonglong2* __restrict__ wp2,
    const ulonglong2* __restrict__ wp3, const float* __restrict__ alpha2,
    const float* __restrict__ bias2, unsigned long long* __restrict__ A3,
    int* __restrict__ sd_g, int* __restrict__ sq_g) {
    const int lane = threadIdx.x & 63;
    const int wib = threadIdx.x >> 6;
    const int nwaves = (gridDim.x * blockDim.x) >> 6;
    int wid = (blockIdx.x * blockDim.x + threadIdx.x) >> 6;

    const ulonglong2 w2 = wp2[lane];
    const ulonglong2 w3a = wp3[lane];
    const ulonglong2 w3b = wp3[lane + 64];
    const float a2 = alpha2[lane], b2 = bias2[lane];
    int sda = 0, sqa = 0, sdb = 0, sqb = 0;
    for (int q = wid; q < P_TOTAL; q += nwaves) {
        unsigned long long A = A2[q];
        int dot2 = __popcll(A & w2.x) - __popcll(A & w2.y);
        float v = a2 * (float)dot2 + b2;
        unsigned long long A3m = __ballot(v > 0.f);
        if (lane == 0) A3[q] = A3m;
        int d3a = __popcll(A3m & w3a.x) - __popcll(A3m & w3a.y);
        int d3b = __popcll(A3m & w3b.x) - __popcll(A3m & w3b.y);
        sda += d3a; sqa += d3a * d3a;
        sdb += d3b; sqb += d3b * d3b;
    }
    __shared__ int rda[4][64], rqa[4][64], rdb[4][64], rqb[4][64];
    rda[wib][lane] = sda; rqa[wib][lane] = sqa;
    rdb[wib][lane] = sdb; rqb[wib][lane] = sqb;
    __syncthreads();
    if (threadIdx.x < 64) {
        int tda = rda[0][lane] + rda[1][lane] + rda[2][lane] + rda[3][lane];
        int tqa = rqa[0][lane] + rqa[1][lane] + rqa[2][lane] + rqa[3][lane];
        int tdb = rdb[0][lane] + rdb[1][lane] + rdb[2][lane] + rdb[3][lane];
        int tqb = rqb[0][lane] + rqb[1][lane] + rqb[2][lane] + rqb[3][lane];
        atomicAdd(&sd_g[lane], tda);
        atomicAdd(&sq_g[lane], tqa);
        atomicAdd(&sd_g[lane + 64], tdb);
        atomicAdd(&sq_g[lane + 64], tqb);
    }
}

// -------- K4: layer-3 values, max over k, ReLU, write output ----------------
__global__ void __launch_bounds__(256) k4_out(
    const unsigned long long* __restrict__ A3, const ulonglong2* __restrict__ wp3,
    const float* __restrict__ alpha3, const float* __restrict__ bias3,
    float* __restrict__ out) {
    const int lane = threadIdx.x & 63;
    const int nwaves = (gridDim.x * blockDim.x) >> 6;
    int wid = (blockIdx.x * blockDim.x + threadIdx.x) >> 6;

    const ulonglong2 wa = wp3[lane];
    const ulonglong2 wb = wp3[lane + 64];
    const float aa = alpha3[lane], ba = bias3[lane];
    const float ab = alpha3[lane + 64], bb = bias3[lane + 64];
    for (int m = wid; m < NROWS; m += nwaves) {
        float ma = -3.0e38f, mb = -3.0e38f;
        for (int k = 0; k < KNEI; ++k) {
            unsigned long long A = A3[m * KNEI + k];
            int da = __popcll(A & wa.x) - __popcll(A & wa.y);
            int db = __popcll(A & wb.x) - __popcll(A & wb.y);
            ma = fmaxf(ma, aa * (float)da + ba);
            mb = fmaxf(mb, ab * (float)db + bb);
        }
        out[(size_t)m * 128 + lane] = fmaxf(ma, 0.f);
        out[(size_t)m * 128 + 64 + lane] = fmaxf(mb, 0.f);
    }
}

extern "C" void kernel_launch(void* const* d_in, const int* in_sizes, int n_in,
                              void* d_out, int out_size, void* d_ws, size_t ws_size,
                              hipStream_t stream) {
    const float* agg = (const float*)d_in[0];
    const float* W1 = (const float*)d_in[1];
    const float* s1 = (const float*)d_in[2];
    const float* g1 = (const float*)d_in[3];
    const float* b1 = (const float*)d_in[4];
    const float* W2 = (const float*)d_in[5];
    const float* s2 = (const float*)d_in[6];
    const float* g2 = (const float*)d_in[7];
    const float* b2 = (const float*)d_in[8];
    const float* W3 = (const float*)d_in[9];
    const float* s3 = (const float*)d_in[10];
    const float* g3 = (const float*)d_in[11];
    const float* b3 = (const float*)d_in[12];
    float* out = (float*)d_out;

    char* ws = (char*)d_ws;
    ulonglong2* wp1 = (ulonglong2*)(ws + 0);            // 64 * 16B
    ulonglong2* wp2 = (ulonglong2*)(ws + 1024);         // 64 * 16B
    ulonglong2* wp3 = (ulonglong2*)(ws + 2048);         // 128 * 16B
    int* stats = (int*)(ws + 4096);                     // 512 ints
    float* params = (float*)(ws + 6144);                // 512 floats
    ulonglong2* A1 = (ulonglong2*)(ws + 8192);                                  // 4 MB
    unsigned long long* A2 = (unsigned long long*)(ws + 8192 + (size_t)P_TOTAL * 16);  // 2 MB
    unsigned long long* A3 = (unsigned long long*)(ws + 8192 + (size_t)P_TOTAL * 24);  // 2 MB

    int* s1d = stats;        int* s1q = stats + 64;
    int* s2d = stats + 128;  int* s2q = stats + 192;
    int* s3d = stats + 256;  int* s3q = stats + 384;
    float* alpha1 = params;        float* bias1 = params + 64;
    float* alpha2 = params + 128;  float* bias2 = params + 192;
    float* alpha3 = params + 256;  float* bias3 = params + 384;

    k0_pack<<<1, 256, 0, stream>>>(W1, W2, W3, wp1, wp2, wp3, stats);
    k1_pack_stats<<<1024, 256, 0, stream>>>(agg, wp1, A1, s1d, s1q);
    kf_finalize<<<1, 64, 0, stream>>>(s1d, s1q, s1, g1, b1, alpha1, bias1, 64);
    k2_bin1_stats2<<<512, 256, 0, stream>>>(A1, wp1, wp2, alpha1, bias1, A2, s2d, s2q);
    kf_finalize<<<1, 64, 0, stream>>>(s2d, s2q, s2, g2, b2, alpha2, bias2, 64);
    k3_bin2_stats3<<<512, 256, 0, stream>>>(A2, wp2, wp3, alpha2, bias2, A3, s3d, s3q);
    kf_finalize<<<1, 128, 0, stream>>>(s3d, s3q, s3, g3, b3, alpha3, bias3, 128);
    k4_out<<<512, 256, 0, stream>>>(A3, wp3, alpha3, bias3, out);
}

// Round 2
// 93.884 us; speedup vs baseline: 2.0201x; 2.0201x over previous
//
#include <hip/hip_runtime.h>

// BiPointNet: 3x (binarized 1x1 conv + BN(batch stats) + ReLU) + maxpool over K.
// B=8, N=1024, K=32, Cin=64, sizes 64->64->64->128. Popcount-GEMM on 64-bit masks.
// v2: batch-of-64 broadcast processing (readlane), float4 input pack, fused BN
// param computation per block, k3 emits per-row dot max/min so k4 is trivial.

typedef unsigned long long u64;

#define P_TOTAL (8192 * 32)
#define NROWS 8192

__device__ __forceinline__ u64 bcast64(u64 x, int p) {
    unsigned lo = __builtin_amdgcn_readlane((unsigned)x, p);
    unsigned hi = __builtin_amdgcn_readlane((unsigned)(x >> 32), p);
    return ((u64)hi << 32) | lo;
}

// fold BN(batch stats)+scale+gamma+beta into v = alpha*dot + bias, per block
__device__ __forceinline__ void compute_params(const int* sd, const int* sq,
        const float* scale, const float* gamma, const float* beta,
        float* sa, float* sb, int C) {
    int t = threadIdx.x;
    if (t < C) {
        const double invN = 1.0 / (double)P_TOTAL;
        double m = (double)sd[t] * invN;
        double var = (double)sq[t] * invN - m * m;
        double sc = (double)scale[t];
        double inv = 1.0 / sqrt(sc * sc * var + 1e-5);
        double g = (double)gamma[t];
        sa[t] = (float)(g * inv * sc);
        sb[t] = (float)((double)beta[t] - g * inv * sc * m);
    }
    __syncthreads();
}

// ---------------- K0: pack weights into bitmasks, zero stats ----------------
// W1 is packed with the k1 ballot permutation: channel c -> bit (c&3)*16 + (c>>2)
__global__ void k0_pack(const float* __restrict__ W1, const float* __restrict__ W2,
                        const float* __restrict__ W3,
                        ulonglong2* __restrict__ wp1, ulonglong2* __restrict__ wp2,
                        ulonglong2* __restrict__ wp3, int* __restrict__ stats) {
    int t = threadIdx.x;
    stats[t] = 0;
    stats[t + 256] = 0;
    if (t < 64) {
        u64 s = 0, nz = 0;
        for (int c = 0; c < 64; ++c) {
            float w = W1[t * 64 + c];
            int p = ((c & 3) << 4) | (c >> 2);
            if (w > 0.f) s |= 1ull << p;
            if (w != 0.f) nz |= 1ull << p;
        }
        wp1[t] = make_ulonglong2(s, nz);
    } else if (t < 128) {
        int o = t - 64;
        u64 pos = 0, neg = 0;
        for (int c = 0; c < 64; ++c) {
            float w = W2[o * 64 + c];
            if (w > 0.f) pos |= 1ull << c;
            if (w < 0.f) neg |= 1ull << c;
        }
        wp2[o] = make_ulonglong2(pos, neg);
    } else {
        int o = t - 128;
        u64 pos = 0, neg = 0;
        for (int c = 0; c < 64; ++c) {
            float w = W3[o * 64 + c];
            if (w > 0.f) pos |= 1ull << c;
            if (w < 0.f) neg |= 1ull << c;
        }
        wp3[o] = make_ulonglong2(pos, neg);
    }
}

// ------------- K1: float4 input pack (8 ballots / 4 positions) + L1 stats ----
__global__ void __launch_bounds__(256) k1_pack_stats(
    const float4* __restrict__ in4, const ulonglong2* __restrict__ wp1,
    ulonglong2* __restrict__ A1, int* __restrict__ sd_g, int* __restrict__ sq_g) {
    const int lane = threadIdx.x & 63;
    const int wib = threadIdx.x >> 6;
    const int wid = (blockIdx.x << 2) | wib;       // 4096 waves
    const ulonglong2 w = wp1[lane];                // permuted sign / nonzero
    const int sh = (lane >> 4) << 4;               // my position-group shift
    int sd = 0, sq = 0;
    for (int b = wid * 16, be = b + 16; b < be; ++b) {   // 16 batches of 4 positions
        const int q0 = b << 2;
        float4 v = in4[(size_t)(q0 << 4) + lane];
        u64 bs0 = __ballot(v.x > 0.f), bn0 = __ballot(v.x != 0.f);
        u64 bs1 = __ballot(v.y > 0.f), bn1 = __ballot(v.y != 0.f);
        u64 bs2 = __ballot(v.z > 0.f), bn2 = __ballot(v.z != 0.f);
        u64 bs3 = __ballot(v.w > 0.f), bn3 = __ballot(v.w != 0.f);
        u64 myS = ((bs0 >> sh) & 0xFFFFull) | (((bs1 >> sh) & 0xFFFFull) << 16)
                | (((bs2 >> sh) & 0xFFFFull) << 32) | (((bs3 >> sh) & 0xFFFFull) << 48);
        u64 myN = ((bn0 >> sh) & 0xFFFFull) | (((bn1 >> sh) & 0xFFFFull) << 16)
                | (((bn2 >> sh) & 0xFFFFull) << 32) | (((bn3 >> sh) & 0xFFFFull) << 48);
        if ((lane & 15) == 0) A1[q0 + (lane >> 4)] = make_ulonglong2(myS, myN);
        #pragma unroll
        for (int p = 0; p < 4; ++p) {              // uniform (SALU) mask assembly
            const int s2 = p << 4;
            u64 as = ((bs0 >> s2) & 0xFFFFull) | (((bs1 >> s2) & 0xFFFFull) << 16)
                   | (((bs2 >> s2) & 0xFFFFull) << 32) | (((bs3 >> s2) & 0xFFFFull) << 48);
            u64 an = ((bn0 >> s2) & 0xFFFFull) | (((bn1 >> s2) & 0xFFFFull) << 16)
                   | (((bn2 >> s2) & 0xFFFFull) << 32) | (((bn3 >> s2) & 0xFFFFull) << 48);
            u64 mnz = an & w.y;
            int dot = __popcll(mnz) - 2 * __popcll(mnz & (as ^ w.x));
            sd += dot; sq += dot * dot;
        }
    }
    __shared__ int rd[4][64], rq[4][64];
    rd[wib][lane] = sd; rq[wib][lane] = sq;
    __syncthreads();
    if (threadIdx.x < 64) {
        atomicAdd(&sd_g[lane], rd[0][lane] + rd[1][lane] + rd[2][lane] + rd[3][lane]);
        atomicAdd(&sq_g[lane], rq[0][lane] + rq[1][lane] + rq[2][lane] + rq[3][lane]);
    }
}

// -------- K2: layer-1 binarize -> A2 masks, layer-2 dot stats ---------------
__global__ void __launch_bounds__(256) k2_bin1_stats2(
    const ulonglong2* __restrict__ A1, const ulonglong2* __restrict__ wp1,
    const ulonglong2* __restrict__ wp2, const int* __restrict__ s1d,
    const int* __restrict__ s1q, const float* __restrict__ scale,
    const float* __restrict__ gamma, const float* __restrict__ beta,
    u64* __restrict__ A2, int* __restrict__ sd_g, int* __restrict__ sq_g) {
    __shared__ float sa[64], sb[64];
    compute_params(s1d, s1q, scale, gamma, beta, sa, sb, 64);
    const int lane = threadIdx.x & 63;
    const int wib = threadIdx.x >> 6;
    const int wid = (blockIdx.x << 2) | wib;       // 2048 waves x 128 positions
    const ulonglong2 w1 = wp1[lane];
    const ulonglong2 w2 = wp2[lane];
    const float a1 = sa[lane], b1 = sb[lane];
    int sd = 0, sq = 0;
    for (int c = 0; c < 2; ++c) {
        const int q0 = wid * 128 + c * 64;
        ulonglong2 a = A1[q0 + lane];              // coalesced 16B/lane
        u64 mymask = 0;
        #pragma unroll 8
        for (int p = 0; p < 64; ++p) {
            u64 as = bcast64(a.x, p);
            u64 an = bcast64(a.y, p);
            u64 mnz = an & w1.y;
            int dot1 = __popcll(mnz) - 2 * __popcll(mnz & (as ^ w1.x));
            float v = fmaf(a1, (float)dot1, b1);
            u64 A = __ballot(v > 0.f);
            mymask = (lane == p) ? A : mymask;
            int dot2 = __popcll(A & w2.x) - __popcll(A & w2.y);
            sd += dot2; sq += dot2 * dot2;
        }
        A2[q0 + lane] = mymask;                    // coalesced 8B/lane
    }
    __shared__ int rd[4][64], rq[4][64];
    rd[wib][lane] = sd; rq[wib][lane] = sq;
    __syncthreads();
    if (threadIdx.x < 64) {
        atomicAdd(&sd_g[lane], rd[0][lane] + rd[1][lane] + rd[2][lane] + rd[3][lane]);
        atomicAdd(&sq_g[lane], rq[0][lane] + rq[1][lane] + rq[2][lane] + rq[3][lane]);
    }
}

// -- K3: layer-2 binarize, layer-3 dots -> stats + per-row dot max/min (int8) -
__global__ void __launch_bounds__(256) k3_bin2_stats3(
    const u64* __restrict__ A2, const ulonglong2* __restrict__ wp2,
    const ulonglong2* __restrict__ wp3, const int* __restrict__ s2d,
    const int* __restrict__ s2q, const float* __restrict__ scale,
    const float* __restrict__ gamma, const float* __restrict__ beta,
    short* __restrict__ dmm, int* __restrict__ sd_g, int* __restrict__ sq_g) {
    __shared__ float sa[64], sb[64];
    compute_params(s2d, s2q, scale, gamma, beta, sa, sb, 64);
    const int lane = threadIdx.x & 63;
    const int wib = threadIdx.x >> 6;
    const int wid = (blockIdx.x << 2) | wib;       // 2048 waves x 4 rows
    const ulonglong2 w2 = wp2[lane];
    const ulonglong2 w3a = wp3[lane];
    const ulonglong2 w3b = wp3[lane + 64];
    const float a2 = sa[lane], b2 = sb[lane];
    int sda = 0, sqa = 0, sdb = 0, sqb = 0;
    for (int c = 0; c < 2; ++c) {
        const int q0 = wid * 128 + c * 64;         // rows q0/32, q0/32+1
        u64 a = A2[q0 + lane];                     // coalesced 8B/lane
        #pragma unroll
        for (int r = 0; r < 2; ++r) {
            int maxa = -127, mina = 127, maxb = -127, minb = 127;
            #pragma unroll 8
            for (int pp = 0; pp < 32; ++pp) {
                const int p = (r << 5) | pp;
                u64 Ap = bcast64(a, p);
                int dot2 = __popcll(Ap & w2.x) - __popcll(Ap & w2.y);
                float v = fmaf(a2, (float)dot2, b2);
                u64 A = __ballot(v > 0.f);
                int da = __popcll(A & w3a.x) - __popcll(A & w3a.y);
                int db = __popcll(A & w3b.x) - __popcll(A & w3b.y);
                sda += da; sqa += da * da; sdb += db; sqb += db * db;
                maxa = max(maxa, da); mina = min(mina, da);
                maxb = max(maxb, db); minb = min(minb, db);
            }
            const int m = (q0 >> 5) + r;
            dmm[m * 128 + lane]      = (short)((maxa & 0xFF) | ((mina & 0xFF) << 8));
            dmm[m * 128 + 64 + lane] = (short)((maxb & 0xFF) | ((minb & 0xFF) << 8));
        }
    }
    __shared__ int rda[4][64], rqa[4][64], rdb[4][64], rqb[4][64];
    rda[wib][lane] = sda; rqa[wib][lane] = sqa;
    rdb[wib][lane] = sdb; rqb[wib][lane] = sqb;
    __syncthreads();
    if (threadIdx.x < 64) {
        atomicAdd(&sd_g[lane], rda[0][lane] + rda[1][lane] + rda[2][lane] + rda[3][lane]);
        atomicAdd(&sq_g[lane], rqa[0][lane] + rqa[1][lane] + rqa[2][lane] + rqa[3][lane]);
        atomicAdd(&sd_g[lane + 64], rdb[0][lane] + rdb[1][lane] + rdb[2][lane] + rdb[3][lane]);
        atomicAdd(&sq_g[lane + 64], rqb[0][lane] + rqb[1][lane] + rqb[2][lane] + rqb[3][lane]);
    }
}

// -------- K4: trivial epilogue: v = alpha*(alpha>=0?dmax:dmin)+bias, ReLU ----
__global__ void __launch_bounds__(256) k4_out(
    const short* __restrict__ dmm, const int* __restrict__ s3d,
    const int* __restrict__ s3q, const float* __restrict__ scale,
    const float* __restrict__ gamma, const float* __restrict__ beta,
    float* __restrict__ out) {
    __shared__ float sa[128], sb[128];
    compute_params(s3d, s3q, scale, gamma, beta, sa, sb, 128);
    const int idx = blockIdx.x * 256 + threadIdx.x;   // m*128 + o
    const int o = idx & 127;
    short pk = dmm[idx];
    int mx = (signed char)(pk & 0xFF);
    int mn = (signed char)((pk >> 8) & 0xFF);
    float a = sa[o], b = sb[o];
    float v = fmaf(a, (float)(a >= 0.f ? mx : mn), b);
    out[idx] = fmaxf(v, 0.f);
}

extern "C" void kernel_launch(void* const* d_in, const int* in_sizes, int n_in,
                              void* d_out, int out_size, void* d_ws, size_t ws_size,
                              hipStream_t stream) {
    const float* agg = (const float*)d_in[0];
    const float* W1 = (const float*)d_in[1];
    const float* s1 = (const float*)d_in[2];
    const float* g1 = (const float*)d_in[3];
    const float* b1 = (const float*)d_in[4];
    const float* W2 = (const float*)d_in[5];
    const float* s2 = (const float*)d_in[6];
    const float* g2 = (const float*)d_in[7];
    const float* b2 = (const float*)d_in[8];
    const float* W3 = (const float*)d_in[9];
    const float* s3 = (const float*)d_in[10];
    const float* g3 = (const float*)d_in[11];
    const float* b3 = (const float*)d_in[12];
    float* out = (float*)d_out;

    char* ws = (char*)d_ws;
    ulonglong2* wp1 = (ulonglong2*)(ws + 0);
    ulonglong2* wp2 = (ulonglong2*)(ws + 1024);
    ulonglong2* wp3 = (ulonglong2*)(ws + 2048);
    int* stats = (int*)(ws + 4096);                                    // 512 ints
    ulonglong2* A1 = (ulonglong2*)(ws + 8192);                         // 4 MB
    u64* A2 = (u64*)(ws + 8192 + (size_t)P_TOTAL * 16);                // 2 MB
    short* dmm = (short*)(ws + 8192 + (size_t)P_TOTAL * 24);           // 2 MB

    int* s1d = stats;        int* s1q = stats + 64;
    int* s2d = stats + 128;  int* s2q = stats + 192;
    int* s3d = stats + 256;  int* s3q = stats + 384;

    k0_pack<<<1, 256, 0, stream>>>(W1, W2, W3, wp1, wp2, wp3, stats);
    k1_pack_stats<<<1024, 256, 0, stream>>>((const float4*)agg, wp1, A1, s1d, s1q);
    k2_bin1_stats2<<<512, 256, 0, stream>>>(A1, wp1, wp2, s1d, s1q, s1, g1, b1, A2, s2d, s2q);
    k3_bin2_stats3<<<512, 256, 0, stream>>>(A2, wp2, wp3, s2d, s2q, s2, g2, b2, dmm, s3d, s3q);
    k4_out<<<4096, 256, 0, stream>>>(dmm, s3d, s3q, s3, g3, b3, out);
}